// Round 8
// baseline (249.628 us; speedup 1.0000x reference)
//
#include <hip/hip_runtime.h>
#include <hip/hip_bf16.h>

// Problem constants
#define BB 2
#define TT 2048
#define DD 1024
#define NN 16
#define RR 64          // DT_RANK
#define MM (BB*TT)     // 4096 rows
#define KDIM DD        // 1024
#define CHUNK 64
#define NCHUNK (TT/CHUNK)  // 32
#define KSPLIT 8
#define NBLK ((DD/64)*NCHUNK*BB)   // 1024 fused-kernel blocks (exactly co-resident)

// Workspace layout (in floats)
#define BT_OFF 0                      // Bt: MM*NN            = 65536 (pre-scaled by rA)
#define CT_OFF 65536                  // Ct: MM*NN            = 65536
#define R1_OFF 131072                 // R1: MM*RR            = 262144
#define P_OFF  393216                 // P : NCHUNK*BB*DD*NN  = 1048576
#define S_OFF  1441792                // S : same             = 1048576
#define PP_OFF 2490368                // Pp: KSPLIT*MM*96     = 3145728
#define BAR_OFF 5636096               // barrier counter (16 floats)

#define LOG2E 1.4426950408889634f

#if __has_builtin(__builtin_amdgcn_exp2f)
#define EXP2(x) __builtin_amdgcn_exp2f(x)
#else
#define EXP2(x) exp2f(x)
#endif

__device__ __forceinline__ float softplus_f(float z) {
    return fmaxf(z, 0.0f) + log1pf(expf(-fabsf(z)));
}

// ---------------------------------------------------------------------------
// Kernel 1: combined projection partials  Pp[p] = x[:, p-slice] @ W^T
// cols = [B(16) | C(16) | dt1(64)].  KSPLIT=8 -> grid (64,8)=512 blocks.
// ---------------------------------------------------------------------------
__global__ __launch_bounds__(256) void k_proj96(
    const float* __restrict__ x, const float* __restrict__ W_B,
    const float* __restrict__ W_C, const float* __restrict__ W_dt1,
    float* __restrict__ Pp)
{
    __shared__ float xs[16][68];
    __shared__ float wsT[16][97];

    const int tid = threadIdx.x;
    const int r0 = blockIdx.x * 64;
    const int kbase = blockIdx.y * (KDIM / KSPLIT);
    const int tx = tid & 15;
    const int ty = tid >> 4;

    float acc[4][6];
    #pragma unroll
    for (int i = 0; i < 4; i++)
        #pragma unroll
        for (int j = 0; j < 6; j++) acc[i][j] = 0.0f;

    for (int kc = 0; kc < KDIM / KSPLIT; kc += 16) {
        {
            const int row = tid >> 2;
            const int kq = (tid & 3) * 4;
            float4 v = *(const float4*)(x + (size_t)(r0 + row) * KDIM + kbase + kc + kq);
            xs[kq + 0][row] = v.x; xs[kq + 1][row] = v.y;
            xs[kq + 2][row] = v.z; xs[kq + 3][row] = v.w;
        }
        #pragma unroll
        for (int i = 0; i < 6; i++) {
            const int idx = i * 256 + tid;
            const int c = idx >> 4;
            const int kk = idx & 15;
            const float* wrow; int cc;
            if (c < 16)      { wrow = W_B;   cc = c; }
            else if (c < 32) { wrow = W_C;   cc = c - 16; }
            else             { wrow = W_dt1; cc = c - 32; }
            wsT[kk][c] = wrow[(size_t)cc * KDIM + kbase + kc + kk];
        }
        __syncthreads();
        #pragma unroll
        for (int kk = 0; kk < 16; kk++) {
            const float a0 = xs[kk][ty * 4 + 0];
            const float a1 = xs[kk][ty * 4 + 1];
            const float a2 = xs[kk][ty * 4 + 2];
            const float a3 = xs[kk][ty * 4 + 3];
            #pragma unroll
            for (int j = 0; j < 6; j++) {
                const float b = wsT[kk][tx + j * 16];
                acc[0][j] = fmaf(a0, b, acc[0][j]);
                acc[1][j] = fmaf(a1, b, acc[1][j]);
                acc[2][j] = fmaf(a2, b, acc[2][j]);
                acc[3][j] = fmaf(a3, b, acc[3][j]);
            }
        }
        __syncthreads();
    }

    float* out = Pp + (size_t)blockIdx.y * (MM * 96);
    #pragma unroll
    for (int i = 0; i < 4; i++) {
        const int r = r0 + ty * 4 + i;
        #pragma unroll
        for (int j = 0; j < 6; j++)
            out[(size_t)r * 96 + tx + j * 16] = acc[i][j];
    }
}

// ---------------------------------------------------------------------------
// Kernel 1b: sum the 8 k-split partials, scatter to Bt | Ct | R1.
// Bt is pre-scaled by rA[n] = 1/(A[n]+1e-8) (n-only).
// ---------------------------------------------------------------------------
__global__ __launch_bounds__(256) void k_reduce96(
    const float* __restrict__ Pp, const float* __restrict__ log_A,
    float* __restrict__ Bt, float* __restrict__ Ct, float* __restrict__ R1)
{
    const int gid = blockIdx.x * 256 + threadIdx.x;   // 0..98303
    const int e0 = gid * 4;
    float4 s = *(const float4*)(Pp + e0);
    #pragma unroll
    for (int p = 1; p < KSPLIT; p++) {
        const float4 v = *(const float4*)(Pp + (size_t)p * MM * 96 + e0);
        s.x += v.x; s.y += v.y; s.z += v.z; s.w += v.w;
    }
    const int r = e0 / 96;
    const int c = e0 - r * 96;
    if (c < 16) {
        const float4 lgj = *(const float4*)(log_A + c);
        s.x *= 1.0f / (-__expf(lgj.x) + 1e-8f);
        s.y *= 1.0f / (-__expf(lgj.y) + 1e-8f);
        s.z *= 1.0f / (-__expf(lgj.z) + 1e-8f);
        s.w *= 1.0f / (-__expf(lgj.w) + 1e-8f);
        *(float4*)(Bt + (size_t)r * NN + c) = s;
    } else if (c < 32) {
        *(float4*)(Ct + (size_t)r * NN + (c - 16)) = s;
    } else {
        *(float4*)(R1 + (size_t)r * RR + (c - 32)) = s;
    }
}

// ---------------------------------------------------------------------------
// Kernel 2: FUSED dt-GEMM + scan1 + grid-barrier + scan2.
// grid (16,32,2)=1024 blocks x 256 thr; LDS exactly 40960B -> 4 blocks/CU
// x 256 CU = 1024 co-resident (barrier-safe); __launch_bounds__(256,4)
// caps VGPR at 128.
// LDS: dt_s[64][64] persistent; pool 24KB aliased:
//   phase0: r1s[64][64] (16KB) + wh[32][64] (8KB)
//   phase1/2: x_s[64][64] (16KB) + bt_s[64][16] + ct_s[64][16] (8KB)
// ---------------------------------------------------------------------------
__global__ __launch_bounds__(256, 4) void k_fused(
    const float* __restrict__ x, const float* __restrict__ R1,
    const float* __restrict__ Bt, const float* __restrict__ Ct,
    const float* __restrict__ W_dt2, const float* __restrict__ b_dt2,
    const float* __restrict__ log_A, const float* __restrict__ D_skip,
    float* __restrict__ P, float* __restrict__ S,
    float* __restrict__ y, int* bar)
{
    __shared__ float dt_s[CHUNK][64];   // 16 KB persistent
    __shared__ float pool[6144];        // 24 KB aliased
    float (*r1s)[64]  = (float (*)[64])pool;
    float (*wh)[64]   = (float (*)[64])(pool + 4096);
    float (*x_s)[64]  = (float (*)[64])pool;
    float (*bt_s)[NN] = (float (*)[NN])(pool + 4096);
    float (*ct_s)[NN] = (float (*)[NN])(pool + 5120);

    const int tid = threadIdx.x;
    const int d0 = blockIdx.x * 64;
    const int c  = blockIdx.y;
    const int b  = blockIdx.z;
    const int base = b * TT + c * CHUNK;

    // ---- phase 0: stage r1s; prefetch x/bt/ct + W halves into registers ----
    #pragma unroll
    for (int i = 0; i < 4; i++) {
        const int f = tid + i * 256;
        const int row = f >> 4;
        const int kq = (f & 15) * 4;
        *(float4*)&r1s[row][kq] = *(const float4*)(R1 + (size_t)(base + row) * RR + kq);
    }
    float4 gw0[2], gw1[2];
    #pragma unroll
    for (int i = 0; i < 2; i++) {
        const int f = tid + i * 256;
        const int dl = f >> 3;
        const int kq = (f & 7) * 4;
        gw0[i] = *(const float4*)(W_dt2 + (size_t)(d0 + dl) * RR + kq);
        gw1[i] = *(const float4*)(W_dt2 + (size_t)(d0 + dl) * RR + 32 + kq);
    }
    float4 gx[4];
    #pragma unroll
    for (int i = 0; i < 4; i++) {
        const int f = tid + i * 256;
        const int t = f >> 4;
        const int j = (f & 15) * 4;
        gx[i] = *(const float4*)(x + (size_t)(base + t) * DD + d0 + j);
    }
    const int tb = tid >> 2;
    const int jb = (tid & 3) * 4;
    const float4 gbt = *(const float4*)(Bt + (size_t)(base + tb) * NN + jb);
    const float4 gct = *(const float4*)(Ct + (size_t)(base + tb) * NN + jb);

    // wh <- kh=0 half (transposed store, one-time 8-way conflict: cheap)
    #pragma unroll
    for (int i = 0; i < 2; i++) {
        const int f = tid + i * 256;
        const int dl = f >> 3;
        const int kq = (f & 7) * 4;
        wh[kq + 0][dl] = gw0[i].x; wh[kq + 1][dl] = gw0[i].y;
        wh[kq + 2][dl] = gw0[i].z; wh[kq + 3][dl] = gw0[i].w;
    }
    __syncthreads();

    // ---- dt-GEMM: dt[t][d] = sum_k r1s[t][k] * W_dt2[d][k] ----
    const int cg = tid & 15;   // cols cg*4..+3
    const int rg = tid >> 4;   // rows rg*4..+3
    float4 acc4[4];
    #pragma unroll
    for (int i = 0; i < 4; i++) acc4[i] = make_float4(0.f, 0.f, 0.f, 0.f);

    #pragma unroll
    for (int k4 = 0; k4 < 8; k4++) {
        float4 aa[4];
        #pragma unroll
        for (int i = 0; i < 4; i++)
            aa[i] = *(const float4*)&r1s[rg * 4 + i][k4 * 4];
        #pragma unroll
        for (int kk = 0; kk < 4; kk++) {
            const float4 wv = *(const float4*)&wh[k4 * 4 + kk][cg * 4];
            #pragma unroll
            for (int i = 0; i < 4; i++) {
                const float a = ((const float*)&aa[i])[kk];
                acc4[i].x = fmaf(a, wv.x, acc4[i].x);
                acc4[i].y = fmaf(a, wv.y, acc4[i].y);
                acc4[i].z = fmaf(a, wv.z, acc4[i].z);
                acc4[i].w = fmaf(a, wv.w, acc4[i].w);
            }
        }
    }
    __syncthreads();
    // wh <- kh=1 half
    #pragma unroll
    for (int i = 0; i < 2; i++) {
        const int f = tid + i * 256;
        const int dl = f >> 3;
        const int kq = (f & 7) * 4;
        wh[kq + 0][dl] = gw1[i].x; wh[kq + 1][dl] = gw1[i].y;
        wh[kq + 2][dl] = gw1[i].z; wh[kq + 3][dl] = gw1[i].w;
    }
    __syncthreads();
    #pragma unroll
    for (int k4 = 0; k4 < 8; k4++) {
        float4 aa[4];
        #pragma unroll
        for (int i = 0; i < 4; i++)
            aa[i] = *(const float4*)&r1s[rg * 4 + i][32 + k4 * 4];
        #pragma unroll
        for (int kk = 0; kk < 4; kk++) {
            const float4 wv = *(const float4*)&wh[k4 * 4 + kk][cg * 4];
            #pragma unroll
            for (int i = 0; i < 4; i++) {
                const float a = ((const float*)&aa[i])[kk];
                acc4[i].x = fmaf(a, wv.x, acc4[i].x);
                acc4[i].y = fmaf(a, wv.y, acc4[i].y);
                acc4[i].z = fmaf(a, wv.z, acc4[i].z);
                acc4[i].w = fmaf(a, wv.w, acc4[i].w);
            }
        }
    }
    __syncthreads();   // all r1s/wh reads done -> pool can be re-used

    // dt_s = softplus(acc + bias)
    {
        const float4 bias = *(const float4*)(b_dt2 + d0 + cg * 4);
        #pragma unroll
        for (int i = 0; i < 4; i++) {
            float4 o;
            o.x = softplus_f(acc4[i].x + bias.x);
            o.y = softplus_f(acc4[i].y + bias.y);
            o.z = softplus_f(acc4[i].z + bias.z);
            o.w = softplus_f(acc4[i].w + bias.w);
            *(float4*)&dt_s[rg * 4 + i][cg * 4] = o;
        }
    }
    // x/bt/ct registers -> pool
    #pragma unroll
    for (int i = 0; i < 4; i++) {
        const int f = tid + i * 256;
        const int t = f >> 4;
        const int j = (f & 15) * 4;
        *(float4*)&x_s[t][j] = gx[i];
    }
    *(float4*)&bt_s[tb][jb] = gbt;   // Bt pre-scaled by rA in k_reduce96
    *(float4*)&ct_s[tb][jb] = gct;
    __syncthreads();

    // ---- phase 1: local scan (S chains + dtsum), write P/S ----
    const int ng = tid & 3;
    const int dl = tid >> 2;
    const int d  = d0 + dl;
    const int n0 = ng * 4;
    const float4 lg = *(const float4*)(log_A + d * NN + n0);
    const float A20 = -__expf(lg.x) * LOG2E, A21 = -__expf(lg.y) * LOG2E,
                A22 = -__expf(lg.z) * LOG2E, A23 = -__expf(lg.w) * LOG2E;
    const float dsk = D_skip[d];

    float S0 = 0.f, S1 = 0.f, S2 = 0.f, S3 = 0.f, dtsum = 0.f;
    #pragma unroll 16
    for (int t = 0; t < CHUNK; t++) {
        const float dtv = dt_s[t][dl];
        const float xv  = x_s[t][dl];
        const float4 bt4 = *(const float4*)&bt_s[t][n0];
        const float a0 = EXP2(dtv * A20);
        const float a1 = EXP2(dtv * A21);
        const float a2 = EXP2(dtv * A22);
        const float a3 = EXP2(dtv * A23);
        const float u0 = xv * bt4.x;
        const float u1 = xv * bt4.y;
        const float u2 = xv * bt4.z;
        const float u3 = xv * bt4.w;
        S0 = fmaf(a0, S0 + u0, -u0);
        S1 = fmaf(a1, S1 + u1, -u1);
        S2 = fmaf(a2, S2 + u2, -u2);
        S3 = fmaf(a3, S3 + u3, -u3);
        dtsum += dtv;
    }
    const int oidx = ((c * BB + b) * DD + d) * NN + n0;
    *(float4*)(P + oidx) = make_float4(EXP2(A20 * dtsum), EXP2(A21 * dtsum),
                                       EXP2(A22 * dtsum), EXP2(A23 * dtsum));
    *(float4*)(S + oidx) = make_float4(S0, S1, S2, S3);

    // ---- grid barrier (all 1024 blocks co-resident by construction) ----
    __syncthreads();
    if (tid == 0) {
        __hip_atomic_fetch_add(bar, 1, __ATOMIC_ACQ_REL, __HIP_MEMORY_SCOPE_AGENT);
        while (__hip_atomic_load(bar, __ATOMIC_ACQUIRE, __HIP_MEMORY_SCOPE_AGENT) < NBLK)
            __builtin_amdgcn_s_sleep(4);
    }
    __syncthreads();

    // ---- phase 2: lookback + final scan, LDS tiles reused ----
    float h0 = 0.f, h1 = 0.f, h2 = 0.f, h3 = 0.f;
    for (int cc = 0; cc < c; cc++) {
        const int idx = ((cc * BB + b) * DD + d) * NN + n0;
        const float4 Pv = *(const float4*)(P + idx);
        const float4 Sv = *(const float4*)(S + idx);
        h0 = fmaf(Pv.x, h0, Sv.x);
        h1 = fmaf(Pv.y, h1, Sv.y);
        h2 = fmaf(Pv.z, h2, Sv.z);
        h3 = fmaf(Pv.w, h3, Sv.w);
    }

    float* yp = y + (size_t)base * DD + d;
    #pragma unroll 16
    for (int t = 0; t < CHUNK; t++) {
        const float dtv = dt_s[t][dl];
        const float xv  = x_s[t][dl];
        const float4 bt4 = *(const float4*)&bt_s[t][n0];
        const float4 ct4 = *(const float4*)&ct_s[t][n0];
        const float a0 = EXP2(dtv * A20);
        const float a1 = EXP2(dtv * A21);
        const float a2 = EXP2(dtv * A22);
        const float a3 = EXP2(dtv * A23);
        const float u0 = xv * bt4.x;
        const float u1 = xv * bt4.y;
        const float u2 = xv * bt4.z;
        const float u3 = xv * bt4.w;
        h0 = fmaf(a0, h0 + u0, -u0);
        h1 = fmaf(a1, h1 + u1, -u1);
        h2 = fmaf(a2, h2 + u2, -u2);
        h3 = fmaf(a3, h3 + u3, -u3);
        float part = fmaf(h3, ct4.w, fmaf(h2, ct4.z, fmaf(h1, ct4.y, h0 * ct4.x)));
        part += __shfl_xor(part, 1);   // DPP quad-perm
        part += __shfl_xor(part, 2);   // DPP quad-perm
        if (ng == 0) yp[(size_t)t * DD] = fmaf(dsk, xv, part);
    }
}

// ---------------------------------------------------------------------------
extern "C" void kernel_launch(void* const* d_in, const int* in_sizes, int n_in,
                              void* d_out, int out_size, void* d_ws, size_t ws_size,
                              hipStream_t stream)
{
    const float* x      = (const float*)d_in[0];
    const float* W_B    = (const float*)d_in[1];
    const float* W_C    = (const float*)d_in[2];
    const float* W_dt1  = (const float*)d_in[3];
    const float* W_dt2  = (const float*)d_in[4];
    const float* b_dt2  = (const float*)d_in[5];
    const float* log_A  = (const float*)d_in[6];
    const float* D_skip = (const float*)d_in[7];
    float* y = (float*)d_out;

    float* ws = (float*)d_ws;
    float* Bt = ws + BT_OFF;
    float* Ct = ws + CT_OFF;
    float* R1 = ws + R1_OFF;
    float* P  = ws + P_OFF;
    float* S  = ws + S_OFF;
    float* Pp = ws + PP_OFF;
    int*   bar = (int*)(ws + BAR_OFF);

    hipMemsetAsync(bar, 0, 64, stream);
    k_proj96<<<dim3(MM / 64, KSPLIT), 256, 0, stream>>>(x, W_B, W_C, W_dt1, Pp);
    k_reduce96<<<dim3(MM * 96 / 4 / 256), 256, 0, stream>>>(Pp, log_A, Bt, Ct, R1);
    k_fused<<<dim3(DD / 64, NCHUNK, BB), 256, 0, stream>>>(
        x, R1, Bt, Ct, W_dt2, b_dt2, log_A, D_skip, P, S, y, bar);
}

// Round 9
// 165.149 us; speedup vs baseline: 1.5115x; 1.5115x over previous
//
#include <hip/hip_runtime.h>
#include <hip/hip_bf16.h>

// Problem constants
#define BB 2
#define TT 2048
#define DD 1024
#define NN 16
#define RR 64          // DT_RANK
#define MM (BB*TT)     // 4096 rows
#define KDIM DD        // 1024
#define CHUNK 64
#define NCHUNK (TT/CHUNK)  // 32
#define KSPLIT 8

// Workspace layout (in floats) — ~39 MB total
#define BT_OFF 0                      // Bt: MM*NN            = 65536 (pre-scaled by rA)
#define CT_OFF 65536                  // Ct: MM*NN            = 65536
#define R1_OFF 131072                 // R1: MM*RR            = 262144
#define DT_OFF 393216                 // dt: MM*DD            = 4194304
#define P_OFF  4587520                // P : NCHUNK*BB*DD*NN  = 1048576
#define S_OFF  5636096                // S : same             = 1048576
#define PP_OFF 6684672                // Pp: KSPLIT*MM*96     = 3145728

#define LOG2E 1.4426950408889634f

#if __has_builtin(__builtin_amdgcn_exp2f)
#define EXP2(x) __builtin_amdgcn_exp2f(x)
#else
#define EXP2(x) exp2f(x)
#endif

__device__ __forceinline__ float softplus_f(float z) {
    return fmaxf(z, 0.0f) + log1pf(expf(-fabsf(z)));
}

// ---------------------------------------------------------------------------
// Kernel 1: combined projection partials  Pp[p] = x[:, p-slice] @ W^T
// cols = [B(16) | C(16) | dt1(64)].  KSPLIT=8 -> grid (64,8)=512 blocks
// (2 blocks/CU, staging latency hidden).
// ---------------------------------------------------------------------------
__global__ __launch_bounds__(256) void k_proj96(
    const float* __restrict__ x, const float* __restrict__ W_B,
    const float* __restrict__ W_C, const float* __restrict__ W_dt1,
    float* __restrict__ Pp)
{
    __shared__ float xs[16][68];
    __shared__ float wsT[16][97];

    const int tid = threadIdx.x;
    const int r0 = blockIdx.x * 64;
    const int kbase = blockIdx.y * (KDIM / KSPLIT);
    const int tx = tid & 15;
    const int ty = tid >> 4;

    float acc[4][6];
    #pragma unroll
    for (int i = 0; i < 4; i++)
        #pragma unroll
        for (int j = 0; j < 6; j++) acc[i][j] = 0.0f;

    for (int kc = 0; kc < KDIM / KSPLIT; kc += 16) {
        {
            const int row = tid >> 2;
            const int kq = (tid & 3) * 4;
            float4 v = *(const float4*)(x + (size_t)(r0 + row) * KDIM + kbase + kc + kq);
            xs[kq + 0][row] = v.x; xs[kq + 1][row] = v.y;
            xs[kq + 2][row] = v.z; xs[kq + 3][row] = v.w;
        }
        #pragma unroll
        for (int i = 0; i < 6; i++) {
            const int idx = i * 256 + tid;
            const int c = idx >> 4;
            const int kk = idx & 15;
            const float* wrow; int cc;
            if (c < 16)      { wrow = W_B;   cc = c; }
            else if (c < 32) { wrow = W_C;   cc = c - 16; }
            else             { wrow = W_dt1; cc = c - 32; }
            wsT[kk][c] = wrow[(size_t)cc * KDIM + kbase + kc + kk];
        }
        __syncthreads();
        #pragma unroll
        for (int kk = 0; kk < 16; kk++) {
            const float a0 = xs[kk][ty * 4 + 0];
            const float a1 = xs[kk][ty * 4 + 1];
            const float a2 = xs[kk][ty * 4 + 2];
            const float a3 = xs[kk][ty * 4 + 3];
            #pragma unroll
            for (int j = 0; j < 6; j++) {
                const float b = wsT[kk][tx + j * 16];
                acc[0][j] = fmaf(a0, b, acc[0][j]);
                acc[1][j] = fmaf(a1, b, acc[1][j]);
                acc[2][j] = fmaf(a2, b, acc[2][j]);
                acc[3][j] = fmaf(a3, b, acc[3][j]);
            }
        }
        __syncthreads();
    }

    float* out = Pp + (size_t)blockIdx.y * (MM * 96);
    #pragma unroll
    for (int i = 0; i < 4; i++) {
        const int r = r0 + ty * 4 + i;
        #pragma unroll
        for (int j = 0; j < 6; j++)
            out[(size_t)r * 96 + tx + j * 16] = acc[i][j];
    }
}

// ---------------------------------------------------------------------------
// Kernel 1b: sum the 8 k-split partials, scatter to Bt | Ct | R1.
// Bt is pre-scaled by rA[n] = 1/(A[n]+1e-8)  (n-only, broadcast over d).
// ---------------------------------------------------------------------------
__global__ __launch_bounds__(256) void k_reduce96(
    const float* __restrict__ Pp, const float* __restrict__ log_A,
    float* __restrict__ Bt, float* __restrict__ Ct, float* __restrict__ R1)
{
    const int gid = blockIdx.x * 256 + threadIdx.x;   // 0..98303
    const int e0 = gid * 4;
    float4 s = *(const float4*)(Pp + e0);
    #pragma unroll
    for (int p = 1; p < KSPLIT; p++) {
        const float4 v = *(const float4*)(Pp + (size_t)p * MM * 96 + e0);
        s.x += v.x; s.y += v.y; s.z += v.z; s.w += v.w;
    }
    const int r = e0 / 96;
    const int c = e0 - r * 96;
    if (c < 16) {
        const float4 lgj = *(const float4*)(log_A + c);
        s.x *= 1.0f / (-__expf(lgj.x) + 1e-8f);
        s.y *= 1.0f / (-__expf(lgj.y) + 1e-8f);
        s.z *= 1.0f / (-__expf(lgj.z) + 1e-8f);
        s.w *= 1.0f / (-__expf(lgj.w) + 1e-8f);
        *(float4*)(Bt + (size_t)r * NN + c) = s;
    } else if (c < 32) {
        *(float4*)(Ct + (size_t)r * NN + (c - 16)) = s;
    } else {
        *(float4*)(R1 + (size_t)r * RR + (c - 32)) = s;
    }
}

// ---------------------------------------------------------------------------
// Kernel 2: dt = softplus(R1 @ W_dt2^T + b_dt2), reading REDUCED R1.
// Block 64 rows x 128 cols; W_dt2 transposed into LDS at staging
// (one-time conflicts, cheap). LDS 49 KB -> 3 blocks/CU; grid (64,8)=512.
// ---------------------------------------------------------------------------
__global__ __launch_bounds__(256) void k_dtproj(
    const float* __restrict__ R1, const float* __restrict__ W_dt2,
    const float* __restrict__ b_dt2, float* __restrict__ dt)
{
    __shared__ float r1s[64][68];    // 17.4 KB
    __shared__ float wsT[64][128];   // 32 KB

    const int tid = threadIdx.x;
    const int r0 = blockIdx.x * 64;
    const int d0 = blockIdx.y * 128;

    // stage R1 tile: 64 rows x 64 k (coalesced float4)
    #pragma unroll
    for (int i = 0; i < 4; i++) {
        const int f = tid + i * 256;
        const int row = f >> 4;
        const int kq = (f & 15) * 4;
        *(float4*)&r1s[row][kq] = *(const float4*)(R1 + (size_t)(r0 + row) * RR + kq);
    }
    // stage W_dt2 transposed: thread (dl = tid>>1, khalf = (tid&1)*32)
    {
        const int dl = tid >> 1;
        const int khalf = (tid & 1) * 32;
        const float* src = W_dt2 + (size_t)(d0 + dl) * RR + khalf;
        #pragma unroll
        for (int kq = 0; kq < 32; kq += 4) {
            const float4 v = *(const float4*)(src + kq);
            wsT[khalf + kq + 0][dl] = v.x;
            wsT[khalf + kq + 1][dl] = v.y;
            wsT[khalf + kq + 2][dl] = v.z;
            wsT[khalf + kq + 3][dl] = v.w;
        }
    }
    __syncthreads();

    const int cg = tid & 15;   // cols d0 + q*64 + cg*4
    const int rg = tid >> 4;   // rows r0 + rg*4 + i

    float4 acc[4][2];
    #pragma unroll
    for (int i = 0; i < 4; i++) {
        acc[i][0] = make_float4(0.f, 0.f, 0.f, 0.f);
        acc[i][1] = make_float4(0.f, 0.f, 0.f, 0.f);
    }

    for (int k4 = 0; k4 < 16; k4++) {
        float r1a[4][4];
        #pragma unroll
        for (int i = 0; i < 4; i++) {
            const float4 v = *(const float4*)&r1s[rg * 4 + i][k4 * 4];
            r1a[i][0] = v.x; r1a[i][1] = v.y; r1a[i][2] = v.z; r1a[i][3] = v.w;
        }
        #pragma unroll
        for (int kk = 0; kk < 4; kk++) {
            const int k = k4 * 4 + kk;
            const float4 w0 = *(const float4*)&wsT[k][cg * 4];
            const float4 w1 = *(const float4*)&wsT[k][64 + cg * 4];
            #pragma unroll
            for (int i = 0; i < 4; i++) {
                const float a = r1a[i][kk];
                acc[i][0].x = fmaf(a, w0.x, acc[i][0].x);
                acc[i][0].y = fmaf(a, w0.y, acc[i][0].y);
                acc[i][0].z = fmaf(a, w0.z, acc[i][0].z);
                acc[i][0].w = fmaf(a, w0.w, acc[i][0].w);
                acc[i][1].x = fmaf(a, w1.x, acc[i][1].x);
                acc[i][1].y = fmaf(a, w1.y, acc[i][1].y);
                acc[i][1].z = fmaf(a, w1.z, acc[i][1].z);
                acc[i][1].w = fmaf(a, w1.w, acc[i][1].w);
            }
        }
    }

    #pragma unroll
    for (int q = 0; q < 2; q++) {
        const float4 bias = *(const float4*)(b_dt2 + d0 + q * 64 + cg * 4);
        #pragma unroll
        for (int i = 0; i < 4; i++) {
            const int row = r0 + rg * 4 + i;
            float4 o;
            o.x = softplus_f(acc[i][q].x + bias.x);
            o.y = softplus_f(acc[i][q].y + bias.y);
            o.z = softplus_f(acc[i][q].z + bias.z);
            o.w = softplus_f(acc[i][q].w + bias.w);
            *(float4*)(dt + (size_t)row * DD + d0 + q * 64 + cg * 4) = o;
        }
    }
}

// ---------------------------------------------------------------------------
// Scan kernels v7 = v6 structure (proven: 256 thr = 64 d x 4 n-groups,
// CHUNK=64, all t-loop operands in LDS, dtsum trick, EXP2), but staging
// reads the REDUCED Bt (pre-scaled) / Ct — no 8x partial re-read.
// ---------------------------------------------------------------------------
__global__ __launch_bounds__(256) void k_scan1(
    const float* __restrict__ x, const float* __restrict__ dt,
    const float* __restrict__ Bt, const float* __restrict__ log_A,
    float* __restrict__ P, float* __restrict__ S)
{
    __shared__ float dt_s[CHUNK][64];   // 16 KB
    __shared__ float x_s[CHUNK][64];    // 16 KB
    __shared__ float bt_s[CHUNK][NN];   // 4 KB (pre-scaled by rA)

    const int tid = threadIdx.x;
    const int ng = tid & 3;
    const int dl = tid >> 2;
    const int d0 = blockIdx.x * 64;
    const int d  = d0 + dl;
    const int c  = blockIdx.y;
    const int b  = blockIdx.z;
    const int n0 = ng * 4;
    const int base = b * TT + c * CHUNK;

    {
        const float* gdt = dt + (size_t)base * DD + d0;
        const float* gx  = x  + (size_t)base * DD + d0;
        #pragma unroll
        for (int k = 0; k < 4; k++) {
            const int f = tid + k * 256;
            const int t = f >> 4;
            const int j = (f & 15) * 4;
            *(float4*)&dt_s[t][j] = *(const float4*)(gdt + (size_t)t * DD + j);
            *(float4*)&x_s[t][j]  = *(const float4*)(gx  + (size_t)t * DD + j);
        }
        const int t = tid >> 2;
        const int jc = (tid & 3) * 4;
        *(float4*)&bt_s[t][jc] = *(const float4*)(Bt + (size_t)(base + t) * NN + jc);
    }

    const float4 lg = *(const float4*)(log_A + d * NN + n0);
    const float A20 = -__expf(lg.x) * LOG2E, A21 = -__expf(lg.y) * LOG2E,
                A22 = -__expf(lg.z) * LOG2E, A23 = -__expf(lg.w) * LOG2E;

    __syncthreads();

    float S0 = 0.f, S1 = 0.f, S2 = 0.f, S3 = 0.f, dtsum = 0.f;

    #pragma unroll 16
    for (int t = 0; t < CHUNK; t++) {
        const float dtv = dt_s[t][dl];
        const float xv  = x_s[t][dl];
        const float4 bt4 = *(const float4*)&bt_s[t][n0];
        const float a0 = EXP2(dtv * A20);
        const float a1 = EXP2(dtv * A21);
        const float a2 = EXP2(dtv * A22);
        const float a3 = EXP2(dtv * A23);
        const float u0 = xv * bt4.x;
        const float u1 = xv * bt4.y;
        const float u2 = xv * bt4.z;
        const float u3 = xv * bt4.w;
        S0 = fmaf(a0, S0 + u0, -u0);
        S1 = fmaf(a1, S1 + u1, -u1);
        S2 = fmaf(a2, S2 + u2, -u2);
        S3 = fmaf(a3, S3 + u3, -u3);
        dtsum += dtv;
    }

    const int oidx = ((c * BB + b) * DD + d) * NN + n0;
    *(float4*)(P + oidx) = make_float4(EXP2(A20 * dtsum), EXP2(A21 * dtsum),
                                       EXP2(A22 * dtsum), EXP2(A23 * dtsum));
    *(float4*)(S + oidx) = make_float4(S0, S1, S2, S3);
}

__global__ __launch_bounds__(256) void k_scan2(
    const float* __restrict__ x, const float* __restrict__ dt,
    const float* __restrict__ Bt, const float* __restrict__ Ct,
    const float* __restrict__ log_A, const float* __restrict__ D_skip,
    const float* __restrict__ P, const float* __restrict__ S,
    float* __restrict__ y)
{
    __shared__ float dt_s[CHUNK][64];   // 16 KB
    __shared__ float x_s[CHUNK][64];    // 16 KB
    __shared__ float bt_s[CHUNK][NN];   // 4 KB (pre-scaled by rA)
    __shared__ float ct_s[CHUNK][NN];   // 4 KB

    const int tid = threadIdx.x;
    const int ng = tid & 3;
    const int dl = tid >> 2;
    const int d0 = blockIdx.x * 64;
    const int d  = d0 + dl;
    const int c  = blockIdx.y;
    const int b  = blockIdx.z;
    const int n0 = ng * 4;
    const int base = b * TT + c * CHUNK;

    {
        const float* gdt = dt + (size_t)base * DD + d0;
        const float* gx  = x  + (size_t)base * DD + d0;
        #pragma unroll
        for (int k = 0; k < 4; k++) {
            const int f = tid + k * 256;
            const int t = f >> 4;
            const int j = (f & 15) * 4;
            *(float4*)&dt_s[t][j] = *(const float4*)(gdt + (size_t)t * DD + j);
            *(float4*)&x_s[t][j]  = *(const float4*)(gx  + (size_t)t * DD + j);
        }
        const int t = tid >> 2;
        const int jc = (tid & 3) * 4;
        *(float4*)&bt_s[t][jc] = *(const float4*)(Bt + (size_t)(base + t) * NN + jc);
        *(float4*)&ct_s[t][jc] = *(const float4*)(Ct + (size_t)(base + t) * NN + jc);
    }

    const float4 lg = *(const float4*)(log_A + d * NN + n0);
    const float A20 = -__expf(lg.x) * LOG2E, A21 = -__expf(lg.y) * LOG2E,
                A22 = -__expf(lg.z) * LOG2E, A23 = -__expf(lg.w) * LOG2E;
    const float dsk = D_skip[d];

    // h_init from previous chunk transitions (L2-resident P/S)
    float h0 = 0.f, h1 = 0.f, h2 = 0.f, h3 = 0.f;
    for (int cc = 0; cc < c; cc++) {
        const int idx = ((cc * BB + b) * DD + d) * NN + n0;
        const float4 Pv = *(const float4*)(P + idx);
        const float4 Sv = *(const float4*)(S + idx);
        h0 = fmaf(Pv.x, h0, Sv.x);
        h1 = fmaf(Pv.y, h1, Sv.y);
        h2 = fmaf(Pv.z, h2, Sv.z);
        h3 = fmaf(Pv.w, h3, Sv.w);
    }
    __syncthreads();

    float* yp = y + (size_t)base * DD + d;

    #pragma unroll 16
    for (int t = 0; t < CHUNK; t++) {
        const float dtv = dt_s[t][dl];
        const float xv  = x_s[t][dl];
        const float4 bt4 = *(const float4*)&bt_s[t][n0];
        const float4 ct4 = *(const float4*)&ct_s[t][n0];
        const float a0 = EXP2(dtv * A20);
        const float a1 = EXP2(dtv * A21);
        const float a2 = EXP2(dtv * A22);
        const float a3 = EXP2(dtv * A23);
        const float u0 = xv * bt4.x;
        const float u1 = xv * bt4.y;
        const float u2 = xv * bt4.z;
        const float u3 = xv * bt4.w;
        h0 = fmaf(a0, h0 + u0, -u0);
        h1 = fmaf(a1, h1 + u1, -u1);
        h2 = fmaf(a2, h2 + u2, -u2);
        h3 = fmaf(a3, h3 + u3, -u3);
        float part = fmaf(h3, ct4.w, fmaf(h2, ct4.z, fmaf(h1, ct4.y, h0 * ct4.x)));
        part += __shfl_xor(part, 1);   // DPP quad-perm
        part += __shfl_xor(part, 2);   // DPP quad-perm
        if (ng == 0) yp[(size_t)t * DD] = fmaf(dsk, xv, part);
    }
}

// ---------------------------------------------------------------------------
extern "C" void kernel_launch(void* const* d_in, const int* in_sizes, int n_in,
                              void* d_out, int out_size, void* d_ws, size_t ws_size,
                              hipStream_t stream)
{
    const float* x      = (const float*)d_in[0];
    const float* W_B    = (const float*)d_in[1];
    const float* W_C    = (const float*)d_in[2];
    const float* W_dt1  = (const float*)d_in[3];
    const float* W_dt2  = (const float*)d_in[4];
    const float* b_dt2  = (const float*)d_in[5];
    const float* log_A  = (const float*)d_in[6];
    const float* D_skip = (const float*)d_in[7];
    float* y = (float*)d_out;

    float* ws = (float*)d_ws;
    float* Bt = ws + BT_OFF;
    float* Ct = ws + CT_OFF;
    float* R1 = ws + R1_OFF;
    float* dt = ws + DT_OFF;
    float* P  = ws + P_OFF;
    float* S  = ws + S_OFF;
    float* Pp = ws + PP_OFF;

    k_proj96<<<dim3(MM / 64, KSPLIT), 256, 0, stream>>>(x, W_B, W_C, W_dt1, Pp);
    k_reduce96<<<dim3(MM * 96 / 4 / 256), 256, 0, stream>>>(Pp, log_A, Bt, Ct, R1);
    k_dtproj<<<dim3(MM / 64, DD / 128), 256, 0, stream>>>(R1, W_dt2, b_dt2, dt);
    k_scan1<<<dim3(DD / 64, NCHUNK, BB), 256, 0, stream>>>(x, dt, Bt, log_A, P, S);
    k_scan2<<<dim3(DD / 64, NCHUNK, BB), 256, 0, stream>>>(x, dt, Bt, Ct, log_A, D_skip, P, S, y);
}